// Round 1
// baseline (382908.643 us; speedup 1.0000x reference)
//
#include <hip/hip_runtime.h>
#include <math.h>

// 2-layer GRU, T=4096, B=64, H=512, input=1. Output = final hidden states (2,64,512) f32.
//
// R1 baseline: one fused kernel launch per timestep (graph of 4097 step nodes).
// Launch t computes: layer0 state t (from h0[t-1]) AND layer1 state t-1 (from
// h1[t-2] and y0[t-1]=h0[t-1]) -- both read only states written by PREVIOUS
// launches, so there is no intra-launch cross-workgroup dependency.
// States ping-pong in d_ws: state s lives in buffer [s&1].
// fp32 VALU compute (accuracy-safe reference path). Later rounds: persistent
// kernel + domain sync + split-bf16 MFMA.

#define TT 4096
#define BB 64
#define HH 512

__device__ __forceinline__ float sigm(float v) { return 1.0f / (1.0f + expf(-v)); }

__global__ __launch_bounds__(256) void zero_k(float* p, int n) {
    int i = blockIdx.x * 256 + threadIdx.x;
    if (i < n) p[i] = 0.0f;
}

// Grid: 256 blocks of 256 threads.
//   blocks [0,128):  layer0, block id -> (j-slice of 16, b-group of 16)
//   blocks [128,256): layer1, same geometry (2x per-thread work: ih + hh dots)
__global__ __launch_bounds__(256) void gru_step(
    const float* __restrict__ x,
    const float* __restrict__ wih0, const float* __restrict__ whh0,
    const float* __restrict__ bih0, const float* __restrict__ bhh0,
    const float* __restrict__ wih1, const float* __restrict__ whh1,
    const float* __restrict__ bih1, const float* __restrict__ bhh1,
    const float* __restrict__ h0_in, float* __restrict__ h0_out,
    const float* __restrict__ h1_in, float* __restrict__ h1_out,
    int t)
{
    const int tid = threadIdx.x;
    const int jl = tid & 15;
    const int bl = tid >> 4;
    const bool isL0 = blockIdx.x < 128;
    const int id = isL0 ? blockIdx.x : (blockIdx.x - 128);
    const int j = (id >> 2) * 16 + jl;   // 32 j-slices of 16
    const int b = (id & 3) * 16 + bl;    // 4 b-groups of 16

    if (isL0) {
        if (t >= TT) return;  // final launch (t==TT) is layer1-only
        const float* hb = &h0_in[(size_t)b * HH];
        const float* wr = &whh0[(size_t)j * HH];
        const float* wz = &whh0[(size_t)(HH + j) * HH];
        const float* wn = &whh0[(size_t)(2 * HH + j) * HH];
        float ar = 0.f, az = 0.f, an = 0.f;
        for (int k = 0; k < HH; k += 4) {
            float4 h4 = *(const float4*)&hb[k];
            float4 r4 = *(const float4*)&wr[k];
            float4 z4 = *(const float4*)&wz[k];
            float4 n4 = *(const float4*)&wn[k];
            ar += r4.x * h4.x; ar += r4.y * h4.y; ar += r4.z * h4.z; ar += r4.w * h4.w;
            az += z4.x * h4.x; az += z4.y * h4.y; az += z4.z * h4.z; az += z4.w * h4.w;
            an += n4.x * h4.x; an += n4.y * h4.y; an += n4.z * h4.z; an += n4.w * h4.w;
        }
        const float xv = x[(size_t)t * BB + b];
        const float r = sigm(xv * wih0[j]          + bih0[j]          + ar + bhh0[j]);
        const float z = sigm(xv * wih0[HH + j]     + bih0[HH + j]     + az + bhh0[HH + j]);
        const float n = tanhf(xv * wih0[2 * HH + j] + bih0[2 * HH + j] + r * (an + bhh0[2 * HH + j]));
        const float hold = hb[j];
        h0_out[(size_t)b * HH + j] = (1.0f - z) * n + z * hold;
    } else {
        if (t == 0) return;  // layer1 step s=t-1 starts at t=1
        const float* yb = &h0_in[(size_t)b * HH];  // y0[t-1] = h0 state t-1
        const float* hb = &h1_in[(size_t)b * HH];  // h1 state t-2
        const float* ir = &wih1[(size_t)j * HH];
        const float* iz = &wih1[(size_t)(HH + j) * HH];
        const float* in_ = &wih1[(size_t)(2 * HH + j) * HH];
        const float* hr = &whh1[(size_t)j * HH];
        const float* hz = &whh1[(size_t)(HH + j) * HH];
        const float* hn = &whh1[(size_t)(2 * HH + j) * HH];
        float air = 0.f, aiz = 0.f, ain = 0.f, ahr = 0.f, ahz = 0.f, ahn = 0.f;
        for (int k = 0; k < HH; k += 4) {
            float4 y4 = *(const float4*)&yb[k];
            float4 h4 = *(const float4*)&hb[k];
            float4 a4 = *(const float4*)&ir[k];
            float4 b4 = *(const float4*)&iz[k];
            float4 c4 = *(const float4*)&in_[k];
            float4 d4 = *(const float4*)&hr[k];
            float4 e4 = *(const float4*)&hz[k];
            float4 f4 = *(const float4*)&hn[k];
            air += a4.x * y4.x; air += a4.y * y4.y; air += a4.z * y4.z; air += a4.w * y4.w;
            aiz += b4.x * y4.x; aiz += b4.y * y4.y; aiz += b4.z * y4.z; aiz += b4.w * y4.w;
            ain += c4.x * y4.x; ain += c4.y * y4.y; ain += c4.z * y4.z; ain += c4.w * y4.w;
            ahr += d4.x * h4.x; ahr += d4.y * h4.y; ahr += d4.z * h4.z; ahr += d4.w * h4.w;
            ahz += e4.x * h4.x; ahz += e4.y * h4.y; ahz += e4.z * h4.z; ahz += e4.w * h4.w;
            ahn += f4.x * h4.x; ahn += f4.y * h4.y; ahn += f4.z * h4.z; ahn += f4.w * h4.w;
        }
        const float r = sigm(air + bih1[j]          + ahr + bhh1[j]);
        const float z = sigm(aiz + bih1[HH + j]     + ahz + bhh1[HH + j]);
        const float n = tanhf(ain + bih1[2 * HH + j] + r * (ahn + bhh1[2 * HH + j]));
        const float hold = hb[j];
        h1_out[(size_t)b * HH + j] = (1.0f - z) * n + z * hold;
    }
}

__global__ __launch_bounds__(256) void copy_out_k(const float* __restrict__ h0f,
                                                  const float* __restrict__ h1f,
                                                  float* __restrict__ out) {
    int i = blockIdx.x * 256 + threadIdx.x;  // grid covers exactly 2*BB*HH
    out[i] = (i < BB * HH) ? h0f[i] : h1f[i - BB * HH];
}

extern "C" void kernel_launch(void* const* d_in, const int* in_sizes, int n_in,
                              void* d_out, int out_size, void* d_ws, size_t ws_size,
                              hipStream_t stream)
{
    const float* x    = (const float*)d_in[0];
    const float* wih0 = (const float*)d_in[1];
    const float* whh0 = (const float*)d_in[2];
    const float* bih0 = (const float*)d_in[3];
    const float* bhh0 = (const float*)d_in[4];
    const float* wih1 = (const float*)d_in[5];
    const float* whh1 = (const float*)d_in[6];
    const float* bih1 = (const float*)d_in[7];
    const float* bhh1 = (const float*)d_in[8];
    float* out = (float*)d_out;
    float* ws  = (float*)d_ws;

    // ws layout (floats): h0 ping-pong [2][64][512], h1 ping-pong [2][64][512] = 512 KB
    float* h0 = ws;
    float* h1 = ws + 2 * BB * HH;

    // Zero both ping-pong sets every call (harness poisons ws once; graph must
    // be self-initializing for replay determinism).
    zero_k<<<(4 * BB * HH + 255) / 256, 256, 0, stream>>>(ws, 4 * BB * HH);

    // Launch t in [0, TT]:
    //   L0 (t<TT):  reads h0 buf[(t+1)&1] (state t-1), writes buf[t&1] (state t)
    //   L1 (t>=1):  computes state s=t-1: reads h1 buf[t&1] (state t-2) and
    //               y0 = h0 buf[(t+1)&1] (state t-1), writes h1 buf[(t+1)&1]
    for (int t = 0; t <= TT; ++t) {
        const float* h0i = h0 + (size_t)((t + 1) & 1) * BB * HH;
        float*       h0o = h0 + (size_t)(t & 1) * BB * HH;
        const float* h1i = h1 + (size_t)(t & 1) * BB * HH;
        float*       h1o = h1 + (size_t)((t + 1) & 1) * BB * HH;
        gru_step<<<256, 256, 0, stream>>>(x, wih0, whh0, bih0, bhh0,
                                          wih1, whh1, bih1, bhh1,
                                          h0i, h0o, h1i, h1o, t);
    }

    // Final states: h0 state 4095 -> buf[1]; h1 state 4095 -> buf[1].
    copy_out_k<<<(2 * BB * HH) / 256, 256, 0, stream>>>(h0 + BB * HH, h1 + BB * HH, out);
}

// Round 2
// 219931.812 us; speedup vs baseline: 1.7410x; 1.7410x over previous
//
#include <hip/hip_runtime.h>
#include <math.h>

// 2-layer GRU, T=4096, B=64, H=512, input=1. Output = final hidden (2,64,512) f32.
//
// R2: per-step launches kept; step kernel rebuilt for coalescing.
//  - weights pre-transposed in ws: w0T[512][1536], w1T[1024][1536]
//    (w1T rows k<512 = wih1 (input side, y0), k>=512 = whh1 (hidden side, h1))
//  - lane = j (coalesced 256B weight reads); b wave/block-uniform -> h via s_load
//  - WG id % 8 = j-group -> same j-slice WGs land on same XCD (round-robin
//    dispatch) -> weights L2-resident per XCD (~1.1 MB/XCD)
// Grid per step: 192 WGs x 256 thr. L0: id<64 (8 jg x 8 bg, 2 b/thread).
// L1: id>=64 (8 jg x 16 bg, 1 b/thread, K=1024).

#define TT 4096
#define BB 64
#define HH 512

__device__ __forceinline__ float sigm(float v) { return 1.0f / (1.0f + expf(-v)); }

__global__ __launch_bounds__(256) void zero_k(float* p, int n) {
    int i = blockIdx.x * 256 + threadIdx.x;
    if (i < n) p[i] = 0.0f;
}

__global__ __launch_bounds__(256) void transpose_w0(const float* __restrict__ whh0,
                                                    float* __restrict__ w0T) {
    int i = blockIdx.x * 256 + threadIdx.x;      // over 512*1536
    int k = i / 1536, j = i - k * 1536;
    w0T[i] = whh0[j * 512 + k];
}

__global__ __launch_bounds__(256) void build_w1T(const float* __restrict__ wih1,
                                                 const float* __restrict__ whh1,
                                                 float* __restrict__ w1T) {
    int i = blockIdx.x * 256 + threadIdx.x;      // over 1024*1536
    int k = i / 1536, j = i - k * 1536;
    w1T[i] = (k < 512) ? wih1[j * 512 + k] : whh1[j * 512 + (k - 512)];
}

__global__ __launch_bounds__(256) void gru_step2(
    const float* __restrict__ x,
    const float* __restrict__ wih0,
    const float* __restrict__ bih0, const float* __restrict__ bhh0,
    const float* __restrict__ bih1, const float* __restrict__ bhh1,
    const float* __restrict__ w0T, const float* __restrict__ w1T,
    const float* __restrict__ h0_in, float* __restrict__ h0_out,
    const float* __restrict__ h1_in, float* __restrict__ h1_out,
    int t)
{
    const int tid = threadIdx.x;
    const int jl  = tid & 63;
    const int wslot = __builtin_amdgcn_readfirstlane(tid >> 6);  // 0..3, wave-uniform SGPR
    const int id = blockIdx.x;

    if (id < 64) {
        // ---- Layer 0: state t from h0[t-1]. 8 jg x 8 bg; thread: j-lane, 2 b.
        if (t >= TT) return;
        const int jg = id & 7, bg = id >> 3;
        const int j  = jg * 64 + jl;
        const int b0 = bg * 8 + wslot * 2;       // b0, b0+1
        const float* ha = &h0_in[(size_t)b0 * HH];
        const float* hb = ha + HH;
        float ar0 = 0.f, az0 = 0.f, an0 = 0.f;
        float ar1 = 0.f, az1 = 0.f, an1 = 0.f;
        #pragma unroll 8
        for (int k = 0; k < HH; ++k) {
            const float* wrow = &w0T[(size_t)k * 1536 + j];
            const float wr = wrow[0], wz = wrow[512], wn = wrow[1024];
            const float h0v = ha[k], h1v = hb[k];
            ar0 += wr * h0v; az0 += wz * h0v; an0 += wn * h0v;
            ar1 += wr * h1v; az1 += wz * h1v; an1 += wn * h1v;
        }
        const float wir = wih0[j], wiz = wih0[512 + j], win = wih0[1024 + j];
        const float br  = bih0[j] + bhh0[j];
        const float bz  = bih0[512 + j] + bhh0[512 + j];
        const float bnx = bih0[1024 + j];
        const float bnh = bhh0[1024 + j];
        {
            const float xv = x[(size_t)t * BB + b0];
            const float r = sigm(xv * wir + br + ar0);
            const float z = sigm(xv * wiz + bz + az0);
            const float n = tanhf(xv * win + bnx + r * (an0 + bnh));
            h0_out[(size_t)b0 * HH + j] = (1.0f - z) * n + z * ha[j];
        }
        {
            const float xv = x[(size_t)t * BB + b0 + 1];
            const float r = sigm(xv * wir + br + ar1);
            const float z = sigm(xv * wiz + bz + az1);
            const float n = tanhf(xv * win + bnx + r * (an1 + bnh));
            h0_out[(size_t)(b0 + 1) * HH + j] = (1.0f - z) * n + z * hb[j];
        }
    } else {
        // ---- Layer 1: state t-1 from y0=h0[t-1], h1[t-2]. 8 jg x 16 bg; 1 b.
        if (t == 0) return;
        const int id2 = id - 64;
        const int jg = id2 & 7, bg = id2 >> 3;   // bg 0..15
        const int j  = jg * 64 + jl;
        const int b  = bg * 4 + wslot;
        const float* yb = &h0_in[(size_t)b * HH];
        const float* hb = &h1_in[(size_t)b * HH];
        float ar = 0.f, az = 0.f, anx = 0.f, anh = 0.f;
        #pragma unroll 8
        for (int k = 0; k < HH; ++k) {
            const float* wrow = &w1T[(size_t)k * 1536 + j];
            const float yv = yb[k];
            ar  += wrow[0]    * yv;
            az  += wrow[512]  * yv;
            anx += wrow[1024] * yv;
        }
        #pragma unroll 8
        for (int k = 0; k < HH; ++k) {
            const float* wrow = &w1T[(size_t)(HH + k) * 1536 + j];
            const float hv = hb[k];
            ar  += wrow[0]    * hv;
            az  += wrow[512]  * hv;
            anh += wrow[1024] * hv;
        }
        const float r = sigm(ar + bih1[j] + bhh1[j]);
        const float z = sigm(az + bih1[512 + j] + bhh1[512 + j]);
        const float n = tanhf(anx + bih1[1024 + j] + r * (anh + bhh1[1024 + j]));
        h1_out[(size_t)b * HH + j] = (1.0f - z) * n + z * hb[j];
    }
}

__global__ __launch_bounds__(256) void copy_out_k(const float* __restrict__ h0f,
                                                  const float* __restrict__ h1f,
                                                  float* __restrict__ out) {
    int i = blockIdx.x * 256 + threadIdx.x;  // grid covers exactly 2*BB*HH
    out[i] = (i < BB * HH) ? h0f[i] : h1f[i - BB * HH];
}

extern "C" void kernel_launch(void* const* d_in, const int* in_sizes, int n_in,
                              void* d_out, int out_size, void* d_ws, size_t ws_size,
                              hipStream_t stream)
{
    const float* x    = (const float*)d_in[0];
    const float* wih0 = (const float*)d_in[1];
    const float* whh0 = (const float*)d_in[2];
    const float* bih0 = (const float*)d_in[3];
    const float* bhh0 = (const float*)d_in[4];
    const float* wih1 = (const float*)d_in[5];
    const float* whh1 = (const float*)d_in[6];
    const float* bih1 = (const float*)d_in[7];
    const float* bhh1 = (const float*)d_in[8];
    float* out = (float*)d_out;
    float* ws  = (float*)d_ws;

    // ws layout (floats):
    //   [0]       h0 ping-pong 2x64x512
    //   [65536]   h1 ping-pong 2x64x512
    //   [131072]  w0T 512x1536
    //   [917504]  w1T 1024x1536            total 2,490,368 f = 9.96 MB
    float* h0  = ws;
    float* h1  = ws + 65536;
    float* w0T = ws + 131072;
    float* w1T = ws + 917504;

    zero_k<<<(4 * BB * HH + 255) / 256, 256, 0, stream>>>(ws, 4 * BB * HH);
    transpose_w0<<<(512 * 1536) / 256, 256, 0, stream>>>(whh0, w0T);
    build_w1T<<<(1024 * 1536) / 256, 256, 0, stream>>>(wih1, whh1, w1T);

    // Launch t in [0, TT]:
    //   L0 (t<TT):  reads h0 buf[(t+1)&1] (state t-1), writes buf[t&1] (state t)
    //   L1 (t>=1):  computes state t-1: reads h1 buf[t&1] (state t-2) and
    //               y0 = h0 buf[(t+1)&1] (state t-1), writes h1 buf[(t+1)&1]
    for (int t = 0; t <= TT; ++t) {
        const float* h0i = h0 + (size_t)((t + 1) & 1) * BB * HH;
        float*       h0o = h0 + (size_t)(t & 1) * BB * HH;
        const float* h1i = h1 + (size_t)(t & 1) * BB * HH;
        float*       h1o = h1 + (size_t)((t + 1) & 1) * BB * HH;
        gru_step2<<<192, 256, 0, stream>>>(x, wih0, bih0, bhh0, bih1, bhh1,
                                           w0T, w1T, h0i, h0o, h1i, h1o, t);
    }

    copy_out_k<<<(2 * BB * HH) / 256, 256, 0, stream>>>(h0 + BB * HH, h1 + BB * HH, out);
}